// Round 4
// baseline (100.722 us; speedup 1.0000x reference)
//
#include <hip/hip_runtime.h>
#include <float.h>

#define N_NODES 200000
#define D 256
#define HID 512
#define OUTD 2
#define NG 512
#define POOL_BLOCKS 2048
#define ROWS_PER_BLK ((N_NODES + POOL_BLOCKS - 1) / POOL_BLOCKS)  // 98

// Monotone float -> u32 encoding: order-preserving, so u32 atomicMax == float max.
__device__ __forceinline__ unsigned enc_f32(float f) {
    unsigned u = __float_as_uint(f);
    return (u & 0x80000000u) ? ~u : (u | 0x80000000u);
}
// decode; u==0 means "never touched" (empty graph) -> 0.0f (matches reference).
__device__ __forceinline__ float dec_f32(unsigned u) {
    if (u == 0u) return 0.f;
    unsigned b = (u & 0x80000000u) ? (u & 0x7FFFFFFFu) : ~u;
    return __uint_as_float(b);
}

__device__ __forceinline__ float4 fmax4(float4 a, float4 b) {
    return make_float4(fmaxf(a.x, b.x), fmaxf(a.y, b.y), fmaxf(a.z, b.z), fmaxf(a.w, b.w));
}

// ---------------------------------------------------------------------------
// Kernel 0: zero the encoded pool buffer (512*256 u32).
// ---------------------------------------------------------------------------
__global__ void k_init(uint4* __restrict__ gp4) {
    gp4[blockIdx.x * blockDim.x + threadIdx.x] = make_uint4(0u, 0u, 0u, 0u);
}

// ---------------------------------------------------------------------------
// Kernel 1: grid-stride segment-max pool via atomicMax on encoded u32.
// 2048 blocks x 256 thr (8 blocks/CU). Block owns rows [b*98, b*98+98).
// Wave w handles rows rbeg+w, +4, ... ; lane owns float4 cols [4l,4l+4).
// Flush running max to gp on graph change (batch sorted -> cheap detection).
// ---------------------------------------------------------------------------
__global__ __launch_bounds__(256) void k_pool(const float* __restrict__ x,
                                              const int* __restrict__ batch,
                                              unsigned* __restrict__ gp) {
    const int lane = threadIdx.x & 63;
    const int wave = threadIdx.x >> 6;
    const int rbeg = blockIdx.x * ROWS_PER_BLK;
    const int rend = min(rbeg + ROWS_PER_BLK, N_NODES);
    const float* xc = x + (size_t)lane * 4;

    const float4 NEUT = make_float4(-FLT_MAX, -FLT_MAX, -FLT_MAX, -FLT_MAX);
    float4 m = NEUT;
    int cur = -1;

    auto flush = [&](int g, float4 mm) {
        unsigned* p = gp + (size_t)g * D + lane * 4;
        atomicMax(p + 0, enc_f32(mm.x));
        atomicMax(p + 1, enc_f32(mm.y));
        atomicMax(p + 2, enc_f32(mm.z));
        atomicMax(p + 3, enc_f32(mm.w));
    };

    int r = rbeg + wave;
    while (r < rend) {
        const int rl = r + 28;
        if (rl < rend && batch[r] == batch[rl]) {
            // fast path: all 8 rows in one graph
            const int bg = batch[r];
            if (bg != cur) {
                if (cur >= 0) flush(cur, m);
                m = NEUT;
                cur = bg;
            }
            float4 v0 = *reinterpret_cast<const float4*>(xc + (size_t)(r)      * D);
            float4 v1 = *reinterpret_cast<const float4*>(xc + (size_t)(r + 4)  * D);
            float4 v2 = *reinterpret_cast<const float4*>(xc + (size_t)(r + 8)  * D);
            float4 v3 = *reinterpret_cast<const float4*>(xc + (size_t)(r + 12) * D);
            float4 v4 = *reinterpret_cast<const float4*>(xc + (size_t)(r + 16) * D);
            float4 v5 = *reinterpret_cast<const float4*>(xc + (size_t)(r + 20) * D);
            float4 v6 = *reinterpret_cast<const float4*>(xc + (size_t)(r + 24) * D);
            float4 v7 = *reinterpret_cast<const float4*>(xc + (size_t)(r + 28) * D);
            m = fmax4(m, fmax4(fmax4(fmax4(v0, v1), fmax4(v2, v3)),
                               fmax4(fmax4(v4, v5), fmax4(v6, v7))));
        } else {
            // general path: boundary or range tail; loads issued up-front
            float4 v[8];
            int bg[8];
            bool ok[8];
#pragma unroll
            for (int j = 0; j < 8; ++j) {
                int rj = r + 4 * j;
                ok[j] = rj < rend;
                int rc = ok[j] ? rj : rend - 1;
                v[j]  = *reinterpret_cast<const float4*>(xc + (size_t)rc * D);
                bg[j] = batch[rc];
            }
#pragma unroll
            for (int j = 0; j < 8; ++j) {
                if (ok[j]) {
                    if (bg[j] != cur) {
                        if (cur >= 0) flush(cur, m);
                        m = NEUT;
                        cur = bg[j];
                    }
                    m = fmax4(m, v[j]);
                }
            }
        }
        r += 32;
    }
    if (cur >= 0) flush(cur, m);
}

// ---------------------------------------------------------------------------
// Kernel 2: MLP over 4 graphs per block (grid = 128).  Decode pooled rows,
// then 3 layers; thread t owns output cols 2t,2t+1 for all 4 rows.
// Weights stream from L2 (float2 coalesced); activations broadcast from LDS.
// ---------------------------------------------------------------------------
__global__ __launch_bounds__(256) void k_mlp(const unsigned* __restrict__ gp,
                                             const float* __restrict__ W1,
                                             const float* __restrict__ b1,
                                             const float* __restrict__ W2,
                                             const float* __restrict__ b2,
                                             const float* __restrict__ W3,
                                             const float* __restrict__ b3,
                                             float* __restrict__ out) {
    const int t    = threadIdx.x;
    const int lane = t & 63;
    const int wave = t >> 6;
    const int g0   = blockIdx.x * 4;

    __shared__ float gr[4 * D];
    __shared__ float h1s[4 * HID];
    __shared__ float h2s[4 * HID];
    __shared__ float fin[4][8];

    // decode 4 pooled rows (4*256 u32) -> LDS
    {
        uint4 u = reinterpret_cast<const uint4*>(gp + (size_t)g0 * D)[t];
        float4 f = make_float4(dec_f32(u.x), dec_f32(u.y), dec_f32(u.z), dec_f32(u.w));
        *reinterpret_cast<float4*>(&gr[t * 4]) = f;
    }
    __syncthreads();

    // ---- layer 1: [4,256] @ [256,512] + b1, relu ----
    {
        float acc[4][2] = {};
        const float* w = W1 + 2 * t;
        for (int k = 0; k < D; k += 4) {
            float2 w0 = *reinterpret_cast<const float2*>(w + (size_t)(k)     * HID);
            float2 w1 = *reinterpret_cast<const float2*>(w + (size_t)(k + 1) * HID);
            float2 w2 = *reinterpret_cast<const float2*>(w + (size_t)(k + 2) * HID);
            float2 w3 = *reinterpret_cast<const float2*>(w + (size_t)(k + 3) * HID);
#pragma unroll
            for (int p = 0; p < 4; ++p) {
                float4 a = *reinterpret_cast<const float4*>(&gr[p * D + k]);
                acc[p][0] += a.x * w0.x + a.y * w1.x + a.z * w2.x + a.w * w3.x;
                acc[p][1] += a.x * w0.y + a.y * w1.y + a.z * w2.y + a.w * w3.y;
            }
        }
        float2 bb = *reinterpret_cast<const float2*>(b1 + 2 * t);
#pragma unroll
        for (int p = 0; p < 4; ++p) {
            h1s[p * HID + 2 * t]     = fmaxf(acc[p][0] + bb.x, 0.f);
            h1s[p * HID + 2 * t + 1] = fmaxf(acc[p][1] + bb.y, 0.f);
        }
    }
    __syncthreads();

    // ---- layer 2: [4,512] @ [512,512] + b2, relu ----
    {
        float acc[4][2] = {};
        const float* w = W2 + 2 * t;
        for (int k = 0; k < HID; k += 4) {
            float2 w0 = *reinterpret_cast<const float2*>(w + (size_t)(k)     * HID);
            float2 w1 = *reinterpret_cast<const float2*>(w + (size_t)(k + 1) * HID);
            float2 w2 = *reinterpret_cast<const float2*>(w + (size_t)(k + 2) * HID);
            float2 w3 = *reinterpret_cast<const float2*>(w + (size_t)(k + 3) * HID);
#pragma unroll
            for (int p = 0; p < 4; ++p) {
                float4 a = *reinterpret_cast<const float4*>(&h1s[p * HID + k]);
                acc[p][0] += a.x * w0.x + a.y * w1.x + a.z * w2.x + a.w * w3.x;
                acc[p][1] += a.x * w0.y + a.y * w1.y + a.z * w2.y + a.w * w3.y;
            }
        }
        float2 bb = *reinterpret_cast<const float2*>(b2 + 2 * t);
#pragma unroll
        for (int p = 0; p < 4; ++p) {
            h2s[p * HID + 2 * t]     = fmaxf(acc[p][0] + bb.x, 0.f);
            h2s[p * HID + 2 * t + 1] = fmaxf(acc[p][1] + bb.y, 0.f);
        }
    }
    __syncthreads();

    // ---- layer 3: [4,512] @ [512,2] + b3 ----
    {
        float4 w = *reinterpret_cast<const float4*>(W3 + 4 * t);  // W3[2t][0..1],W3[2t+1][0..1]
        float pv[4][2];
#pragma unroll
        for (int p = 0; p < 4; ++p) {
            float2 h = *reinterpret_cast<const float2*>(&h2s[p * HID + 2 * t]);
            pv[p][0] = h.x * w.x + h.y * w.z;
            pv[p][1] = h.x * w.y + h.y * w.w;
        }
#pragma unroll
        for (int off = 32; off; off >>= 1) {
#pragma unroll
            for (int p = 0; p < 4; ++p) {
                pv[p][0] += __shfl_xor(pv[p][0], off);
                pv[p][1] += __shfl_xor(pv[p][1], off);
            }
        }
        if (lane == 0) {
#pragma unroll
            for (int p = 0; p < 4; ++p) {
                fin[wave][p * 2]     = pv[p][0];
                fin[wave][p * 2 + 1] = pv[p][1];
            }
        }
        __syncthreads();
        if (t < 8) {
            int p = t >> 1, c = t & 1;
            float s = fin[0][t] + fin[1][t] + fin[2][t] + fin[3][t] + b3[c];
            out[(size_t)(g0 + p) * OUTD + c] = s;
        }
    }
}

// ---------------------------------------------------------------------------
extern "C" void kernel_launch(void* const* d_in, const int* in_sizes, int n_in,
                              void* d_out, int out_size, void* d_ws, size_t ws_size,
                              hipStream_t stream) {
    const float* x     = (const float*)d_in[0];
    const int*   batch = (const int*)d_in[1];
    const float* W1    = (const float*)d_in[2];
    const float* b1    = (const float*)d_in[3];
    const float* W2    = (const float*)d_in[4];
    const float* b2    = (const float*)d_in[5];
    const float* W3    = (const float*)d_in[6];
    const float* b3    = (const float*)d_in[7];
    float* out = (float*)d_out;

    unsigned* gp_enc = (unsigned*)d_ws;   // NG * D u32 = 512 KB

    // NG*D/4 uint4 = 32768 -> 128 blocks x 256 thr
    k_init<<<NG * D / 4 / 256, 256, 0, stream>>>((uint4*)gp_enc);
    k_pool<<<POOL_BLOCKS, 256, 0, stream>>>(x, batch, gp_enc);
    k_mlp<<<NG / 4, 256, 0, stream>>>(gp_enc, W1, b1, W2, b2, W3, b3, out);
}

// Round 5
// 94.414 us; speedup vs baseline: 1.0668x; 1.0668x over previous
//
#include <hip/hip_runtime.h>
#include <float.h>

#define N_NODES 200000
#define D 256
#define HID 512
#define OUTD 2
#define NG 512
#define RPW 25                       // rows per wave; 8000 * 25 == N_NODES exactly
#define NWAVES (N_NODES / RPW)       // 8000
#define POOL_BLOCKS (NWAVES / 4)     // 2000 blocks x 4 waves

__device__ __forceinline__ float4 fmax4(float4 a, float4 b) {
    return make_float4(fmaxf(a.x, b.x), fmaxf(a.y, b.y), fmaxf(a.z, b.z), fmaxf(a.w, b.w));
}

// ---------------------------------------------------------------------------
// Cooperative 64-ary lower bound: smallest i with a[i] >= v (may return n).
// All 64 lanes of the calling wave must be active. (Proven in R2.)
// ---------------------------------------------------------------------------
__device__ __forceinline__ int lower_bound_64ary(const int* __restrict__ a, int n,
                                                 int v, int lane) {
    int lo = -1, hi = n;
    while (hi - lo > 1) {
        int len = hi - lo;
        int off = 1 + (int)(((long long)lane * (len - 1)) >> 6);
        int p = lo + off;
        bool lt = a[p] < v;
        unsigned long long m = __ballot(lt);
        int cnt = __popcll(m);
        int nlo = (cnt == 0) ? lo : lo + 1 + (int)(((long long)(cnt - 1) * (len - 1)) >> 6);
        int nhi = (cnt == 64) ? hi : lo + 1 + (int)(((long long)cnt * (len - 1)) >> 6);
        lo = nlo; hi = nhi;
    }
    return hi;
}

// ---------------------------------------------------------------------------
// Kernel 1: pooling phase A. Wave w owns rows [w*25, w*25+25) (contiguous).
// Partial maxima: first graph of the wave -> scrA[w]; last graph -> scrB[w];
// strictly-interior graphs (complete within this wave) -> gp[g] directly.
// No atomics; every slot phase B reads is written by exactly one wave.
// ---------------------------------------------------------------------------
__global__ __launch_bounds__(256) void k_pool(const float* __restrict__ x,
                                              const int* __restrict__ batch,
                                              float* __restrict__ scrA,
                                              float* __restrict__ scrB,
                                              float* __restrict__ gp) {
    const int lane = threadIdx.x & 63;
    const int w    = blockIdx.x * 4 + (threadIdx.x >> 6);
    const int a    = w * RPW;
    const float* xc = x + (size_t)a * D + lane * 4;
    const float4 NEUT = make_float4(-FLT_MAX, -FLT_MAX, -FLT_MAX, -FLT_MAX);

    const int gF = batch[a];
    const int gL = batch[a + RPW - 1];

    if (gF == gL) {
        // fast path (~94% of waves): whole range is one graph
        float4 m = NEUT;
#pragma unroll
        for (int grp = 0; grp < 5; ++grp) {
            const float* base = xc + (size_t)grp * 5 * D;
            float4 v0 = *reinterpret_cast<const float4*>(base + 0 * D);
            float4 v1 = *reinterpret_cast<const float4*>(base + 1 * D);
            float4 v2 = *reinterpret_cast<const float4*>(base + 2 * D);
            float4 v3 = *reinterpret_cast<const float4*>(base + 3 * D);
            float4 v4 = *reinterpret_cast<const float4*>(base + 4 * D);
            m = fmax4(m, fmax4(fmax4(fmax4(v0, v1), fmax4(v2, v3)), v4));
        }
        *reinterpret_cast<float4*>(scrA + (size_t)w * D + lane * 4) = m;
    } else {
        // slow path: 2+ graphs in range
        float4 m = NEUT;
        int cur = gF;
#pragma unroll
        for (int grp = 0; grp < 5; ++grp) {
            const int r = a + grp * 5;
            const float* base = xc + (size_t)grp * 5 * D;
            float4 v[5];
            v[0] = *reinterpret_cast<const float4*>(base + 0 * D);
            v[1] = *reinterpret_cast<const float4*>(base + 1 * D);
            v[2] = *reinterpret_cast<const float4*>(base + 2 * D);
            v[3] = *reinterpret_cast<const float4*>(base + 3 * D);
            v[4] = *reinterpret_cast<const float4*>(base + 4 * D);
            const int b0 = batch[r], b4 = batch[r + 4];
            if (b0 == cur && b4 == cur) {
                m = fmax4(m, fmax4(fmax4(fmax4(v[0], v[1]), fmax4(v[2], v[3])), v[4]));
            } else {
#pragma unroll
                for (int j = 0; j < 5; ++j) {
                    const int bg = batch[r + j];
                    if (bg != cur) {
                        float* dst = (cur == gF) ? scrA + (size_t)w * D
                                                 : gp   + (size_t)cur * D;  // interior: complete
                        *reinterpret_cast<float4*>(dst + lane * 4) = m;
                        m = NEUT;
                        cur = bg;
                    }
                    m = fmax4(m, v[j]);
                }
            }
        }
        // final flush: cur == gL (gL != gF here)
        *reinterpret_cast<float4*>(scrB + (size_t)w * D + lane * 4) = m;
    }
}

// ---------------------------------------------------------------------------
// Kernel 2: phase B (reduce partials) + 3-layer MLP. 128 blocks x 4 graphs.
// Wave p reduces graph g0+p's partials into LDS, then all threads run the MLP
// (thread t owns output cols 2t,2t+1 for all 4 rows; weights stream from L2).
// ---------------------------------------------------------------------------
__global__ __launch_bounds__(256) void k_mlp(const int* __restrict__ batch,
                                             const float* __restrict__ scrA,
                                             const float* __restrict__ scrB,
                                             const float* __restrict__ gp,
                                             const float* __restrict__ W1,
                                             const float* __restrict__ b1,
                                             const float* __restrict__ W2,
                                             const float* __restrict__ b2,
                                             const float* __restrict__ W3,
                                             const float* __restrict__ b3,
                                             float* __restrict__ out) {
    const int t    = threadIdx.x;
    const int lane = t & 63;
    const int wave = t >> 6;
    const int g0   = blockIdx.x * 4;

    __shared__ float gr[4 * D];
    __shared__ float h1s[4 * HID];
    __shared__ float h2s[4 * HID];
    __shared__ float fin[4][8];

    // ---- phase B: per-wave reduce of graph (g0+wave)'s partials ----
    {
        const int g = g0 + wave;
        const int s = lower_bound_64ary(batch, N_NODES, g, lane);
        const int e = lower_bound_64ary(batch, N_NODES, g + 1, lane);
        float4 m = make_float4(0.f, 0.f, 0.f, 0.f);          // empty graph -> zeros
        if (e > s) {
            m = make_float4(-FLT_MAX, -FLT_MAX, -FLT_MAX, -FLT_MAX);
            const int wf = s / RPW, wl = (e - 1) / RPW;
            for (int wv = wf; wv <= wl; ++wv) {
                const int gFw = batch[wv * RPW];
                const float* src;
                if (gFw == g) {
                    src = scrA + (size_t)wv * D;
                } else {
                    const int gLw = batch[wv * RPW + RPW - 1];
                    src = (gLw == g) ? scrB + (size_t)wv * D : gp + (size_t)g * D;
                }
                float4 v = *reinterpret_cast<const float4*>(src + lane * 4);
                m = fmax4(m, v);
            }
        }
        *reinterpret_cast<float4*>(&gr[wave * D + lane * 4]) = m;
    }
    __syncthreads();

    // ---- layer 1: [4,256] @ [256,512] + b1, relu ----
    {
        float acc[4][2] = {};
        const float* w = W1 + 2 * t;
        for (int k = 0; k < D; k += 4) {
            float2 w0 = *reinterpret_cast<const float2*>(w + (size_t)(k)     * HID);
            float2 w1 = *reinterpret_cast<const float2*>(w + (size_t)(k + 1) * HID);
            float2 w2 = *reinterpret_cast<const float2*>(w + (size_t)(k + 2) * HID);
            float2 w3 = *reinterpret_cast<const float2*>(w + (size_t)(k + 3) * HID);
#pragma unroll
            for (int p = 0; p < 4; ++p) {
                float4 aa = *reinterpret_cast<const float4*>(&gr[p * D + k]);
                acc[p][0] += aa.x * w0.x + aa.y * w1.x + aa.z * w2.x + aa.w * w3.x;
                acc[p][1] += aa.x * w0.y + aa.y * w1.y + aa.z * w2.y + aa.w * w3.y;
            }
        }
        float2 bb = *reinterpret_cast<const float2*>(b1 + 2 * t);
#pragma unroll
        for (int p = 0; p < 4; ++p) {
            h1s[p * HID + 2 * t]     = fmaxf(acc[p][0] + bb.x, 0.f);
            h1s[p * HID + 2 * t + 1] = fmaxf(acc[p][1] + bb.y, 0.f);
        }
    }
    __syncthreads();

    // ---- layer 2: [4,512] @ [512,512] + b2, relu ----
    {
        float acc[4][2] = {};
        const float* w = W2 + 2 * t;
        for (int k = 0; k < HID; k += 4) {
            float2 w0 = *reinterpret_cast<const float2*>(w + (size_t)(k)     * HID);
            float2 w1 = *reinterpret_cast<const float2*>(w + (size_t)(k + 1) * HID);
            float2 w2 = *reinterpret_cast<const float2*>(w + (size_t)(k + 2) * HID);
            float2 w3 = *reinterpret_cast<const float2*>(w + (size_t)(k + 3) * HID);
#pragma unroll
            for (int p = 0; p < 4; ++p) {
                float4 aa = *reinterpret_cast<const float4*>(&h1s[p * HID + k]);
                acc[p][0] += aa.x * w0.x + aa.y * w1.x + aa.z * w2.x + aa.w * w3.x;
                acc[p][1] += aa.x * w0.y + aa.y * w1.y + aa.z * w2.y + aa.w * w3.y;
            }
        }
        float2 bb = *reinterpret_cast<const float2*>(b2 + 2 * t);
#pragma unroll
        for (int p = 0; p < 4; ++p) {
            h2s[p * HID + 2 * t]     = fmaxf(acc[p][0] + bb.x, 0.f);
            h2s[p * HID + 2 * t + 1] = fmaxf(acc[p][1] + bb.y, 0.f);
        }
    }
    __syncthreads();

    // ---- layer 3: [4,512] @ [512,2] + b3 ----
    {
        float4 w = *reinterpret_cast<const float4*>(W3 + 4 * t);
        float pv[4][2];
#pragma unroll
        for (int p = 0; p < 4; ++p) {
            float2 h = *reinterpret_cast<const float2*>(&h2s[p * HID + 2 * t]);
            pv[p][0] = h.x * w.x + h.y * w.z;
            pv[p][1] = h.x * w.y + h.y * w.w;
        }
#pragma unroll
        for (int off = 32; off; off >>= 1) {
#pragma unroll
            for (int p = 0; p < 4; ++p) {
                pv[p][0] += __shfl_xor(pv[p][0], off);
                pv[p][1] += __shfl_xor(pv[p][1], off);
            }
        }
        if (lane == 0) {
#pragma unroll
            for (int p = 0; p < 4; ++p) {
                fin[wave][p * 2]     = pv[p][0];
                fin[wave][p * 2 + 1] = pv[p][1];
            }
        }
        __syncthreads();
        if (t < 8) {
            int p = t >> 1, c = t & 1;
            float s = fin[0][t] + fin[1][t] + fin[2][t] + fin[3][t] + b3[c];
            out[(size_t)(g0 + p) * OUTD + c] = s;
        }
    }
}

// ---------------------------------------------------------------------------
extern "C" void kernel_launch(void* const* d_in, const int* in_sizes, int n_in,
                              void* d_out, int out_size, void* d_ws, size_t ws_size,
                              hipStream_t stream) {
    const float* x     = (const float*)d_in[0];
    const int*   batch = (const int*)d_in[1];
    const float* W1    = (const float*)d_in[2];
    const float* b1    = (const float*)d_in[3];
    const float* W2    = (const float*)d_in[4];
    const float* b2    = (const float*)d_in[5];
    const float* W3    = (const float*)d_in[6];
    const float* b3    = (const float*)d_in[7];
    float* out = (float*)d_out;

    char* ws = (char*)d_ws;
    float* scrA = (float*)ws;                                    // 8000*256*4 = 8.192 MB
    float* scrB = (float*)(ws + (size_t)NWAVES * D * 4);         // 8.192 MB
    float* gp   = (float*)(ws + 2 * (size_t)NWAVES * D * 4);     // 512*256*4 = 0.5 MB

    k_pool<<<POOL_BLOCKS, 256, 0, stream>>>(x, batch, scrA, scrB, gp);
    k_mlp<<<NG / 4, 256, 0, stream>>>(batch, scrA, scrB, gp,
                                      W1, b1, W2, b2, W3, b3, out);
}

// Round 6
// 86.134 us; speedup vs baseline: 1.1694x; 1.0961x over previous
//
#include <hip/hip_runtime.h>
#include <float.h>

#define N_NODES 200000
#define D 256
#define HID 512
#define OUTD 2
#define NG 512

__device__ __forceinline__ float4 fmax4(float4 a, float4 b) {
    return make_float4(fmaxf(a.x, b.x), fmaxf(a.y, b.y), fmaxf(a.z, b.z), fmaxf(a.w, b.w));
}

// ---------------------------------------------------------------------------
// Kernel 1: segment boundaries from sorted batch vector (one pass, proven R1).
// row_start[g] = first i with batch[i] >= g; row_start[NG] = N.
// ---------------------------------------------------------------------------
__global__ void k_bounds(const int* __restrict__ batch, int* __restrict__ row_start, int n) {
    int i = blockIdx.x * blockDim.x + threadIdx.x;
    if (i >= n) return;
    int b  = batch[i];
    int bp = (i == 0) ? -1 : batch[i - 1];
    for (int g = bp + 1; g <= b; ++g) row_start[g] = i;
    if (i == n - 1) {
        for (int g = b + 1; g <= NG; ++g) row_start[g] = n;
    }
}

// ---------------------------------------------------------------------------
// Kernel 2: per-graph segment max pool. One block per graph (512 blocks,
// 2/CU). Wave w takes rows r0+w, +4, ...; lane owns float4 cols [4l,4l+4).
// Fully predicated 8-deep loop: OOB rows clamp to r1-1 (same graph, so the
// duplicate fmax is a no-op) -> no serial tail, uniform trip count.
// ---------------------------------------------------------------------------
__global__ __launch_bounds__(256) void k_pool(const float* __restrict__ x,
                                              const int* __restrict__ rs,
                                              float* __restrict__ gp) {
    const int g    = blockIdx.x;
    const int lane = threadIdx.x & 63;
    const int wave = threadIdx.x >> 6;
    const int r0 = rs[g];
    const int r1 = rs[g + 1];
    const int len = r1 - r0;

    float4 m = make_float4(-FLT_MAX, -FLT_MAX, -FLT_MAX, -FLT_MAX);

    if (len > 0) {
        const int rlast = r1 - 1;
        const float* xc = x + (size_t)lane * 4;
        const int iters = (len + 31) >> 5;        // 32 rows per block-iteration
        int base = r0 + wave;
        for (int k = 0; k < iters; ++k) {
            const int b = base + (k << 5);
            const int i0 = min(b,      rlast);
            const int i1 = min(b + 4,  rlast);
            const int i2 = min(b + 8,  rlast);
            const int i3 = min(b + 12, rlast);
            const int i4 = min(b + 16, rlast);
            const int i5 = min(b + 20, rlast);
            const int i6 = min(b + 24, rlast);
            const int i7 = min(b + 28, rlast);
            float4 v0 = *reinterpret_cast<const float4*>(xc + (size_t)i0 * D);
            float4 v1 = *reinterpret_cast<const float4*>(xc + (size_t)i1 * D);
            float4 v2 = *reinterpret_cast<const float4*>(xc + (size_t)i2 * D);
            float4 v3 = *reinterpret_cast<const float4*>(xc + (size_t)i3 * D);
            float4 v4 = *reinterpret_cast<const float4*>(xc + (size_t)i4 * D);
            float4 v5 = *reinterpret_cast<const float4*>(xc + (size_t)i5 * D);
            float4 v6 = *reinterpret_cast<const float4*>(xc + (size_t)i6 * D);
            float4 v7 = *reinterpret_cast<const float4*>(xc + (size_t)i7 * D);
            m = fmax4(m, fmax4(fmax4(fmax4(v0, v1), fmax4(v2, v3)),
                               fmax4(fmax4(v4, v5), fmax4(v6, v7))));
        }
    }

    __shared__ float4 red[4][64];
    red[wave][lane] = m;
    __syncthreads();
    if (wave == 0) {
        float4 o = fmax4(fmax4(red[0][lane], red[1][lane]),
                         fmax4(red[2][lane], red[3][lane]));
        if (len == 0) o = make_float4(0.f, 0.f, 0.f, 0.f);   // empty graph -> zeros
        *reinterpret_cast<float4*>(gp + (size_t)g * D + lane * 4) = o;
    }
}

// ---------------------------------------------------------------------------
// Kernel 3: MLP over 4 graphs per block (grid = 128). Proven in R4.
// Thread t owns output cols 2t,2t+1 for all 4 rows; weights stream from L2
// (float2 coalesced); activations broadcast from LDS.
// ---------------------------------------------------------------------------
__global__ __launch_bounds__(256) void k_mlp(const float* __restrict__ gp,
                                             const float* __restrict__ W1,
                                             const float* __restrict__ b1,
                                             const float* __restrict__ W2,
                                             const float* __restrict__ b2,
                                             const float* __restrict__ W3,
                                             const float* __restrict__ b3,
                                             float* __restrict__ out) {
    const int t    = threadIdx.x;
    const int lane = t & 63;
    const int wave = t >> 6;
    const int g0   = blockIdx.x * 4;

    __shared__ float gr[4 * D];
    __shared__ float h1s[4 * HID];
    __shared__ float h2s[4 * HID];
    __shared__ float fin[4][8];

    // load 4 pooled rows -> LDS
    {
        float4 f = reinterpret_cast<const float4*>(gp + (size_t)g0 * D)[t];
        *reinterpret_cast<float4*>(&gr[t * 4]) = f;
    }
    __syncthreads();

    // ---- layer 1: [4,256] @ [256,512] + b1, relu ----
    {
        float acc[4][2] = {};
        const float* w = W1 + 2 * t;
        for (int k = 0; k < D; k += 4) {
            float2 w0 = *reinterpret_cast<const float2*>(w + (size_t)(k)     * HID);
            float2 w1 = *reinterpret_cast<const float2*>(w + (size_t)(k + 1) * HID);
            float2 w2 = *reinterpret_cast<const float2*>(w + (size_t)(k + 2) * HID);
            float2 w3 = *reinterpret_cast<const float2*>(w + (size_t)(k + 3) * HID);
#pragma unroll
            for (int p = 0; p < 4; ++p) {
                float4 a = *reinterpret_cast<const float4*>(&gr[p * D + k]);
                acc[p][0] += a.x * w0.x + a.y * w1.x + a.z * w2.x + a.w * w3.x;
                acc[p][1] += a.x * w0.y + a.y * w1.y + a.z * w2.y + a.w * w3.y;
            }
        }
        float2 bb = *reinterpret_cast<const float2*>(b1 + 2 * t);
#pragma unroll
        for (int p = 0; p < 4; ++p) {
            h1s[p * HID + 2 * t]     = fmaxf(acc[p][0] + bb.x, 0.f);
            h1s[p * HID + 2 * t + 1] = fmaxf(acc[p][1] + bb.y, 0.f);
        }
    }
    __syncthreads();

    // ---- layer 2: [4,512] @ [512,512] + b2, relu ----
    {
        float acc[4][2] = {};
        const float* w = W2 + 2 * t;
        for (int k = 0; k < HID; k += 4) {
            float2 w0 = *reinterpret_cast<const float2*>(w + (size_t)(k)     * HID);
            float2 w1 = *reinterpret_cast<const float2*>(w + (size_t)(k + 1) * HID);
            float2 w2 = *reinterpret_cast<const float2*>(w + (size_t)(k + 2) * HID);
            float2 w3 = *reinterpret_cast<const float2*>(w + (size_t)(k + 3) * HID);
#pragma unroll
            for (int p = 0; p < 4; ++p) {
                float4 a = *reinterpret_cast<const float4*>(&h1s[p * HID + k]);
                acc[p][0] += a.x * w0.x + a.y * w1.x + a.z * w2.x + a.w * w3.x;
                acc[p][1] += a.x * w0.y + a.y * w1.y + a.z * w2.y + a.w * w3.y;
            }
        }
        float2 bb = *reinterpret_cast<const float2*>(b2 + 2 * t);
#pragma unroll
        for (int p = 0; p < 4; ++p) {
            h2s[p * HID + 2 * t]     = fmaxf(acc[p][0] + bb.x, 0.f);
            h2s[p * HID + 2 * t + 1] = fmaxf(acc[p][1] + bb.y, 0.f);
        }
    }
    __syncthreads();

    // ---- layer 3: [4,512] @ [512,2] + b3 ----
    {
        float4 w = *reinterpret_cast<const float4*>(W3 + 4 * t);
        float pv[4][2];
#pragma unroll
        for (int p = 0; p < 4; ++p) {
            float2 h = *reinterpret_cast<const float2*>(&h2s[p * HID + 2 * t]);
            pv[p][0] = h.x * w.x + h.y * w.z;
            pv[p][1] = h.x * w.y + h.y * w.w;
        }
#pragma unroll
        for (int off = 32; off; off >>= 1) {
#pragma unroll
            for (int p = 0; p < 4; ++p) {
                pv[p][0] += __shfl_xor(pv[p][0], off);
                pv[p][1] += __shfl_xor(pv[p][1], off);
            }
        }
        if (lane == 0) {
#pragma unroll
            for (int p = 0; p < 4; ++p) {
                fin[wave][p * 2]     = pv[p][0];
                fin[wave][p * 2 + 1] = pv[p][1];
            }
        }
        __syncthreads();
        if (t < 8) {
            int p = t >> 1, c = t & 1;
            float s = fin[0][t] + fin[1][t] + fin[2][t] + fin[3][t] + b3[c];
            out[(size_t)(g0 + p) * OUTD + c] = s;
        }
    }
}

// ---------------------------------------------------------------------------
extern "C" void kernel_launch(void* const* d_in, const int* in_sizes, int n_in,
                              void* d_out, int out_size, void* d_ws, size_t ws_size,
                              hipStream_t stream) {
    const float* x     = (const float*)d_in[0];
    const int*   batch = (const int*)d_in[1];
    const float* W1    = (const float*)d_in[2];
    const float* b1    = (const float*)d_in[3];
    const float* W2    = (const float*)d_in[4];
    const float* b2    = (const float*)d_in[5];
    const float* W3    = (const float*)d_in[6];
    const float* b3    = (const float*)d_in[7];
    float* out = (float*)d_out;

    char* ws = (char*)d_ws;
    int*   row_start = (int*)ws;            // 513 ints
    float* gp        = (float*)(ws + 4096); // 512*256 f32 = 512 KB

    k_bounds<<<(N_NODES + 255) / 256, 256, 0, stream>>>(batch, row_start, N_NODES);
    k_pool<<<NG, 256, 0, stream>>>(x, row_start, gp);
    k_mlp<<<NG / 4, 256, 0, stream>>>(gp, W1, b1, W2, b2, W3, b3, out);
}

// Round 7
// 84.260 us; speedup vs baseline: 1.1954x; 1.0222x over previous
//
#include <hip/hip_runtime.h>
#include <float.h>

#define N_NODES 200000
#define D 256
#define HID 512
#define OUTD 2
#define NG 512

__device__ __forceinline__ float4 fmax4(float4 a, float4 b) {
    return make_float4(fmaxf(a.x, b.x), fmaxf(a.y, b.y), fmaxf(a.z, b.z), fmaxf(a.w, b.w));
}

// ---------------------------------------------------------------------------
// Kernel 1: segment boundaries from sorted batch (verbatim from R1 config).
// ---------------------------------------------------------------------------
__global__ void k_bounds(const int* __restrict__ batch, int* __restrict__ row_start, int n) {
    int i = blockIdx.x * blockDim.x + threadIdx.x;
    if (i >= n) return;
    int b  = batch[i];
    int bp = (i == 0) ? -1 : batch[i - 1];
    for (int g = bp + 1; g <= b; ++g) row_start[g] = i;
    if (i == n - 1) {
        for (int g = b + 1; g <= NG; ++g) row_start[g] = n;
    }
}

// ---------------------------------------------------------------------------
// Kernel 2: per-graph segment max pool (verbatim from R1 config: 512 blocks,
// 4 waves stride rows by 4, 4-deep unroll, serial remainder tail).
// ---------------------------------------------------------------------------
__global__ __launch_bounds__(256) void k_pool(const float* __restrict__ x,
                                              const int* __restrict__ rs,
                                              float* __restrict__ gp) {
    const int g    = blockIdx.x;
    const int lane = threadIdx.x & 63;
    const int wave = threadIdx.x >> 6;
    const int r0 = rs[g];
    const int r1 = rs[g + 1];

    float4 m = make_float4(-FLT_MAX, -FLT_MAX, -FLT_MAX, -FLT_MAX);
    const float* xc = x + (size_t)lane * 4;

    int r = r0 + wave;
    for (; r + 12 < r1; r += 16) {
        float4 v0 = *reinterpret_cast<const float4*>(xc + (size_t)r * D);
        float4 v1 = *reinterpret_cast<const float4*>(xc + (size_t)(r + 4) * D);
        float4 v2 = *reinterpret_cast<const float4*>(xc + (size_t)(r + 8) * D);
        float4 v3 = *reinterpret_cast<const float4*>(xc + (size_t)(r + 12) * D);
        m.x = fmaxf(m.x, fmaxf(fmaxf(v0.x, v1.x), fmaxf(v2.x, v3.x)));
        m.y = fmaxf(m.y, fmaxf(fmaxf(v0.y, v1.y), fmaxf(v2.y, v3.y)));
        m.z = fmaxf(m.z, fmaxf(fmaxf(v0.z, v1.z), fmaxf(v2.z, v3.z)));
        m.w = fmaxf(m.w, fmaxf(fmaxf(v0.w, v1.w), fmaxf(v2.w, v3.w)));
    }
    for (; r < r1; r += 4) {
        float4 v = *reinterpret_cast<const float4*>(xc + (size_t)r * D);
        m.x = fmaxf(m.x, v.x); m.y = fmaxf(m.y, v.y);
        m.z = fmaxf(m.z, v.z); m.w = fmaxf(m.w, v.w);
    }

    __shared__ float4 red[4][64];
    red[wave][lane] = m;
    __syncthreads();
    if (wave == 0) {
        float4 a = red[0][lane], b = red[1][lane], c = red[2][lane], d = red[3][lane];
        float4 o;
        o.x = fmaxf(fmaxf(a.x, b.x), fmaxf(c.x, d.x));
        o.y = fmaxf(fmaxf(a.y, b.y), fmaxf(c.y, d.y));
        o.z = fmaxf(fmaxf(a.z, b.z), fmaxf(c.z, d.z));
        o.w = fmaxf(fmaxf(a.w, b.w), fmaxf(c.w, d.w));
        if (r1 == r0) o = make_float4(0.f, 0.f, 0.f, 0.f);  // empty graph -> zeros
        *reinterpret_cast<float4*>(gp + (size_t)g * D + lane * 4) = o;
    }
}

// ---------------------------------------------------------------------------
// Kernel 3: fused 3-layer MLP. 128 blocks x 512 threads (2 waves/SIMD).
// 4 graphs/block; thread-group grp = t>>8 handles graphs {2grp, 2grp+1};
// thread tg = t&255 owns output cols {2tg, 2tg+1}. Both groups load the SAME
// weight addresses (L1/L2 constructive sharing). Activations broadcast from
// LDS (same-address reads, conflict-free).
// ---------------------------------------------------------------------------
__global__ __launch_bounds__(512) void k_mlp(const float* __restrict__ gp,
                                             const float* __restrict__ W1,
                                             const float* __restrict__ b1,
                                             const float* __restrict__ W2,
                                             const float* __restrict__ b2,
                                             const float* __restrict__ W3,
                                             const float* __restrict__ b3,
                                             float* __restrict__ out) {
    const int t    = threadIdx.x;
    const int tg   = t & 255;
    const int grp  = t >> 8;            // 0 or 1
    const int lane = t & 63;
    const int wave = t >> 6;            // 0..7 (waves 0-3 = grp 0, 4-7 = grp 1)
    const int g0   = blockIdx.x * 4;
    const int p0   = grp * 2;           // this group's local graphs: p0, p0+1

    __shared__ float gr[4][D];          // 4 KB
    __shared__ float h1s[4][HID];       // 8 KB
    __shared__ float h2s[4][HID];       // 8 KB
    __shared__ float fin[8][4];

    if (t < 256) {
        float4 f = reinterpret_cast<const float4*>(gp + (size_t)g0 * D)[t];
        *reinterpret_cast<float4*>(&gr[0][0] + t * 4) = f;
    }
    __syncthreads();

    // ---- layer 1: [4,256] @ [256,512] + b1, relu ----
    {
        float a00 = 0.f, a01 = 0.f, a10 = 0.f, a11 = 0.f;
        const float* w = W1 + 2 * tg;
#pragma unroll 2
        for (int k = 0; k < D; k += 4) {
            float2 w0 = *reinterpret_cast<const float2*>(w + (size_t)(k)     * HID);
            float2 w1 = *reinterpret_cast<const float2*>(w + (size_t)(k + 1) * HID);
            float2 w2 = *reinterpret_cast<const float2*>(w + (size_t)(k + 2) * HID);
            float2 w3 = *reinterpret_cast<const float2*>(w + (size_t)(k + 3) * HID);
            float4 xa = *reinterpret_cast<const float4*>(&gr[p0][k]);
            float4 xb = *reinterpret_cast<const float4*>(&gr[p0 + 1][k]);
            a00 += xa.x * w0.x + xa.y * w1.x + xa.z * w2.x + xa.w * w3.x;
            a01 += xa.x * w0.y + xa.y * w1.y + xa.z * w2.y + xa.w * w3.y;
            a10 += xb.x * w0.x + xb.y * w1.x + xb.z * w2.x + xb.w * w3.x;
            a11 += xb.x * w0.y + xb.y * w1.y + xb.z * w2.y + xb.w * w3.y;
        }
        float2 bb = *reinterpret_cast<const float2*>(b1 + 2 * tg);
        h1s[p0][2 * tg]         = fmaxf(a00 + bb.x, 0.f);
        h1s[p0][2 * tg + 1]     = fmaxf(a01 + bb.y, 0.f);
        h1s[p0 + 1][2 * tg]     = fmaxf(a10 + bb.x, 0.f);
        h1s[p0 + 1][2 * tg + 1] = fmaxf(a11 + bb.y, 0.f);
    }
    __syncthreads();

    // ---- layer 2: [4,512] @ [512,512] + b2, relu ----
    {
        float a00 = 0.f, a01 = 0.f, a10 = 0.f, a11 = 0.f;
        const float* w = W2 + 2 * tg;
#pragma unroll 2
        for (int k = 0; k < HID; k += 4) {
            float2 w0 = *reinterpret_cast<const float2*>(w + (size_t)(k)     * HID);
            float2 w1 = *reinterpret_cast<const float2*>(w + (size_t)(k + 1) * HID);
            float2 w2 = *reinterpret_cast<const float2*>(w + (size_t)(k + 2) * HID);
            float2 w3 = *reinterpret_cast<const float2*>(w + (size_t)(k + 3) * HID);
            float4 xa = *reinterpret_cast<const float4*>(&h1s[p0][k]);
            float4 xb = *reinterpret_cast<const float4*>(&h1s[p0 + 1][k]);
            a00 += xa.x * w0.x + xa.y * w1.x + xa.z * w2.x + xa.w * w3.x;
            a01 += xa.x * w0.y + xa.y * w1.y + xa.z * w2.y + xa.w * w3.y;
            a10 += xb.x * w0.x + xb.y * w1.x + xb.z * w2.x + xb.w * w3.x;
            a11 += xb.x * w0.y + xb.y * w1.y + xb.z * w2.y + xb.w * w3.y;
        }
        float2 bb = *reinterpret_cast<const float2*>(b2 + 2 * tg);
        h2s[p0][2 * tg]         = fmaxf(a00 + bb.x, 0.f);
        h2s[p0][2 * tg + 1]     = fmaxf(a01 + bb.y, 0.f);
        h2s[p0 + 1][2 * tg]     = fmaxf(a10 + bb.x, 0.f);
        h2s[p0 + 1][2 * tg + 1] = fmaxf(a11 + bb.y, 0.f);
    }
    __syncthreads();

    // ---- layer 3: [4,512] @ [512,2] + b3 ----
    {
        // thread tg covers k = 2tg, 2tg+1 for its group's 2 graphs
        float4 w = *reinterpret_cast<const float4*>(W3 + 4 * tg);
        float pv[2][2];
#pragma unroll
        for (int p = 0; p < 2; ++p) {
            float2 h = *reinterpret_cast<const float2*>(&h2s[p0 + p][2 * tg]);
            pv[p][0] = h.x * w.x + h.y * w.z;
            pv[p][1] = h.x * w.y + h.y * w.w;
        }
#pragma unroll
        for (int off = 32; off; off >>= 1) {
#pragma unroll
            for (int p = 0; p < 2; ++p) {
                pv[p][0] += __shfl_xor(pv[p][0], off);
                pv[p][1] += __shfl_xor(pv[p][1], off);
            }
        }
        if (lane == 0) {
            fin[wave][0] = pv[0][0]; fin[wave][1] = pv[0][1];
            fin[wave][2] = pv[1][0]; fin[wave][3] = pv[1][1];
        }
        __syncthreads();
        if (t < 8) {
            const int grp2 = t >> 2;          // group
            const int idx  = t & 3;           // p*2 + c
            const int p = idx >> 1, c = idx & 1;
            float s = fin[grp2 * 4 + 0][idx] + fin[grp2 * 4 + 1][idx]
                    + fin[grp2 * 4 + 2][idx] + fin[grp2 * 4 + 3][idx];
            out[(size_t)(g0 + grp2 * 2 + p) * OUTD + c] = s + b3[c];
        }
    }
}

// ---------------------------------------------------------------------------
extern "C" void kernel_launch(void* const* d_in, const int* in_sizes, int n_in,
                              void* d_out, int out_size, void* d_ws, size_t ws_size,
                              hipStream_t stream) {
    const float* x     = (const float*)d_in[0];
    const int*   batch = (const int*)d_in[1];
    const float* W1    = (const float*)d_in[2];
    const float* b1    = (const float*)d_in[3];
    const float* W2    = (const float*)d_in[4];
    const float* b2    = (const float*)d_in[5];
    const float* W3    = (const float*)d_in[6];
    const float* b3    = (const float*)d_in[7];
    float* out = (float*)d_out;

    char* ws = (char*)d_ws;
    int*   row_start = (int*)ws;            // 513 ints
    float* gp        = (float*)(ws + 4096); // 512*256 f32 = 512 KB

    k_bounds<<<(N_NODES + 255) / 256, 256, 0, stream>>>(batch, row_start, N_NODES);
    k_pool<<<NG, 256, 0, stream>>>(x, row_start, gp);
    k_mlp<<<NG / 4, 512, 0, stream>>>(gp, W1, b1, W2, b2, W3, b3, out);
}

// Round 8
// 67.431 us; speedup vs baseline: 1.4937x; 1.2496x over previous
//
#include <hip/hip_runtime.h>
#include <float.h>

#define N_NODES 200000
#define D 256
#define HID 512
#define OUTD 2
#define NG 512

__device__ __forceinline__ float4 fmax4(float4 a, float4 b) {
    return make_float4(fmaxf(a.x, b.x), fmaxf(a.y, b.y), fmaxf(a.z, b.z), fmaxf(a.w, b.w));
}
__device__ __forceinline__ float4 shflx4(float4 v, int mask) {
    return make_float4(__shfl_xor(v.x, mask), __shfl_xor(v.y, mask),
                       __shfl_xor(v.z, mask), __shfl_xor(v.w, mask));
}

// ---------------------------------------------------------------------------
// Kernel 1: segment boundaries from sorted batch (verbatim R1).
// ---------------------------------------------------------------------------
__global__ void k_bounds(const int* __restrict__ batch, int* __restrict__ row_start, int n) {
    int i = blockIdx.x * blockDim.x + threadIdx.x;
    if (i >= n) return;
    int b  = batch[i];
    int bp = (i == 0) ? -1 : batch[i - 1];
    for (int g = bp + 1; g <= b; ++g) row_start[g] = i;
    if (i == n - 1) {
        for (int g = b + 1; g <= NG; ++g) row_start[g] = n;
    }
}

// ---------------------------------------------------------------------------
// Kernel 2: per-graph segment max pool with CONTIGUOUS wave fronts.
// One block per graph. Lane l owns cols [(l&15)*16, +16) and reads 64 B
// contiguous; 16 lanes span one 1 KB row; wave = 4 consecutive rows (4 KB
// dense); block iter = 16 consecutive rows (16 KB dense). Tail rows clamp to
// r1-1 (same graph -> duplicate fmax no-op). Reduce: shfl_xor(16,32) + LDS.
// ---------------------------------------------------------------------------
__global__ __launch_bounds__(256) void k_pool(const float* __restrict__ x,
                                              const int* __restrict__ rs,
                                              float* __restrict__ gp) {
    const int g    = blockIdx.x;
    const int t    = threadIdx.x;
    const int lane = t & 63;
    const int wave = t >> 6;
    const int r0 = rs[g];
    const int r1 = rs[g + 1];
    const int len = r1 - r0;

    const float4 NEUT = make_float4(-FLT_MAX, -FLT_MAX, -FLT_MAX, -FLT_MAX);
    float4 m0 = NEUT, m1 = NEUT, m2 = NEUT, m3 = NEUT;

    if (len > 0) {
        const int rlast = r1 - 1;
        const int sub = lane >> 4;            // 0..3: row within wave's 4-row group
        const int cq  = (lane & 15) * 16;     // col start (floats)
        const int iters = (len + 15) >> 4;    // 16 rows per block-iteration
        for (int i = 0; i < iters; ++i) {
            int row = r0 + i * 16 + wave * 4 + sub;
            row = min(row, rlast);
            const float* p = x + (size_t)row * D + cq;
            float4 v0 = *reinterpret_cast<const float4*>(p);
            float4 v1 = *reinterpret_cast<const float4*>(p + 4);
            float4 v2 = *reinterpret_cast<const float4*>(p + 8);
            float4 v3 = *reinterpret_cast<const float4*>(p + 12);
            m0 = fmax4(m0, v0); m1 = fmax4(m1, v1);
            m2 = fmax4(m2, v2); m3 = fmax4(m3, v3);
        }
    }

    // combine lanes sharing the same col range (l, l^16, l^32, l^48)
    m0 = fmax4(m0, shflx4(m0, 16)); m0 = fmax4(m0, shflx4(m0, 32));
    m1 = fmax4(m1, shflx4(m1, 16)); m1 = fmax4(m1, shflx4(m1, 32));
    m2 = fmax4(m2, shflx4(m2, 16)); m2 = fmax4(m2, shflx4(m2, 32));
    m3 = fmax4(m3, shflx4(m3, 16)); m3 = fmax4(m3, shflx4(m3, 32));

    __shared__ float red[4][16][16];          // [wave][colgrp][elem]
    if (lane < 16) {
        *reinterpret_cast<float4*>(&red[wave][lane][0])  = m0;
        *reinterpret_cast<float4*>(&red[wave][lane][4])  = m1;
        *reinterpret_cast<float4*>(&red[wave][lane][8])  = m2;
        *reinterpret_cast<float4*>(&red[wave][lane][12]) = m3;
    }
    __syncthreads();
    {
        const int cg = t >> 4, e = t & 15;    // col = cg*16 + e = t
        float o = fmaxf(fmaxf(red[0][cg][e], red[1][cg][e]),
                        fmaxf(red[2][cg][e], red[3][cg][e]));
        gp[(size_t)g * D + t] = (len > 0) ? o : 0.f;
    }
}

// ---------------------------------------------------------------------------
// Kernel 3: 32x32-tile f32 GEMM (verbatim R1 config).
// ---------------------------------------------------------------------------
template <int K, bool RELU>
__global__ __launch_bounds__(256) void k_gemm(const float* __restrict__ A,
                                              const float* __restrict__ B,
                                              const float* __restrict__ bias,
                                              float* __restrict__ C, int N) {
    __shared__ float As[32][33];
    __shared__ float Bs[32][33];
    const int t  = threadIdx.x;
    const int bm = blockIdx.y * 32;
    const int bn = blockIdx.x * 32;
    const int lr = t >> 3;
    const int lc = (t & 7) << 2;
    const int tx = t & 15;
    const int ty = t >> 4;
    float acc00 = 0.f, acc01 = 0.f, acc10 = 0.f, acc11 = 0.f;

    for (int k0 = 0; k0 < K; k0 += 32) {
        float4 av = *reinterpret_cast<const float4*>(A + (size_t)(bm + lr) * K + k0 + lc);
        float4 bv = *reinterpret_cast<const float4*>(B + (size_t)(k0 + lr) * N + bn + lc);
        __syncthreads();
        As[lr][lc] = av.x; As[lr][lc + 1] = av.y; As[lr][lc + 2] = av.z; As[lr][lc + 3] = av.w;
        Bs[lr][lc] = bv.x; Bs[lr][lc + 1] = bv.y; Bs[lr][lc + 2] = bv.z; Bs[lr][lc + 3] = bv.w;
        __syncthreads();
#pragma unroll
        for (int kk = 0; kk < 32; ++kk) {
            float a0 = As[ty * 2][kk], a1 = As[ty * 2 + 1][kk];
            float b0 = Bs[kk][tx * 2], b1 = Bs[kk][tx * 2 + 1];
            acc00 += a0 * b0; acc01 += a0 * b1;
            acc10 += a1 * b0; acc11 += a1 * b1;
        }
    }

    const int r = bm + ty * 2, c = bn + tx * 2;
    float bc0 = bias[c], bc1 = bias[c + 1];
    float v00 = acc00 + bc0, v01 = acc01 + bc1;
    float v10 = acc10 + bc0, v11 = acc11 + bc1;
    if (RELU) {
        v00 = fmaxf(v00, 0.f); v01 = fmaxf(v01, 0.f);
        v10 = fmaxf(v10, 0.f); v11 = fmaxf(v11, 0.f);
    }
    C[(size_t)r * N + c]           = v00;
    C[(size_t)r * N + c + 1]       = v01;
    C[(size_t)(r + 1) * N + c]     = v10;
    C[(size_t)(r + 1) * N + c + 1] = v11;
}

// ---------------------------------------------------------------------------
// Kernel 4: final [512,HID] @ [HID,2] + b3 (verbatim R1 config).
// ---------------------------------------------------------------------------
__global__ __launch_bounds__(256) void k_fc3(const float* __restrict__ h,
                                             const float* __restrict__ W,
                                             const float* __restrict__ b,
                                             float* __restrict__ out) {
    const int wave = threadIdx.x >> 6;
    const int lane = threadIdx.x & 63;
    const int e = blockIdx.x * 4 + wave;
    const int row = e >> 1, col = e & 1;
    float s = 0.f;
#pragma unroll
    for (int k = lane; k < HID; k += 64)
        s += h[(size_t)row * HID + k] * W[(size_t)k * OUTD + col];
#pragma unroll
    for (int off = 32; off; off >>= 1) s += __shfl_xor(s, off);
    if (lane == 0) out[e] = s + b[col];
}

// ---------------------------------------------------------------------------
extern "C" void kernel_launch(void* const* d_in, const int* in_sizes, int n_in,
                              void* d_out, int out_size, void* d_ws, size_t ws_size,
                              hipStream_t stream) {
    const float* x     = (const float*)d_in[0];
    const int*   batch = (const int*)d_in[1];
    const float* W1    = (const float*)d_in[2];
    const float* b1    = (const float*)d_in[3];
    const float* W2    = (const float*)d_in[4];
    const float* b2    = (const float*)d_in[5];
    const float* W3    = (const float*)d_in[6];
    const float* b3    = (const float*)d_in[7];
    float* out = (float*)d_out;

    char* ws = (char*)d_ws;
    int*   row_start = (int*)ws;                                   // 513 ints
    float* gp = (float*)(ws + 4096);                               // 512 KB
    float* h1 = (float*)(ws + 4096 + 512 * 1024);                  // 1 MB
    float* h2 = (float*)(ws + 4096 + 512 * 1024 + 1024 * 1024);    // 1 MB

    k_bounds<<<(N_NODES + 255) / 256, 256, 0, stream>>>(batch, row_start, N_NODES);
    k_pool<<<NG, 256, 0, stream>>>(x, row_start, gp);
    k_gemm<D,   true ><<<dim3(HID / 32, NG / 32), 256, 0, stream>>>(gp, W1, b1, h1, HID);
    k_gemm<HID, true ><<<dim3(HID / 32, NG / 32), 256, 0, stream>>>(h1, W2, b2, h2, HID);
    k_fc3<<<NG * OUTD / 4, 256, 0, stream>>>(h2, W3, b3, out);
}